// Round 1
// baseline (205.372 us; speedup 1.0000x reference)
//
#include <hip/hip_runtime.h>

#define HH 256
#define WW 256
#define HWSZ (HH*WW)
#define CC 64
#define GG 4
#define GC 16
#define KK 3
#define PP 9
#define NB 2

__global__ __launch_bounds__(256) void misc_filter_kernel(
    const float* __restrict__ img,
    const float* __restrict__ kv,
    const float* __restrict__ kh,
    const float* __restrict__ off,
    const float* __restrict__ wgt,
    float* __restrict__ out)
{
    // 2048 blocks, 8 XCDs -> each XCD gets one contiguous (b,g) chunk of 256 rows
    int phys = blockIdx.x;
    int logical = (phys & 7) * (NB*GG*HH/8) + (phys >> 3);
    int y  = logical & (HH - 1);
    int bg = logical >> 8;          // [0, NB*GG)
    int g  = bg & (GG - 1);
    int b  = bg >> 2;
    int x  = threadIdx.x;

    const float* imgp = img + (size_t)(b*CC + g*GC) * HWSZ;   // group's first plane
    int pix = y*WW + x;
    const float* offp = off + (size_t)(b*GG*PP*2 + g*PP*2) * HWSZ + pix;
    const float* wgtp = wgt + (size_t)(b*GG*PP   + g*PP  ) * HWSZ + pix;
    const float* khp  = kh  + (size_t)(b*GG*KK   + g*KK  ) * HWSZ + pix;
    const float* kvp  = kv  + (size_t)(b*KK) * HWSZ + pix;

    float khr[KK], kvr[KK];
#pragma unroll
    for (int i = 0; i < KK; ++i) { khr[i] = khp[i*HWSZ]; kvr[i] = kvp[i*HWSZ]; }

    float acc[GC];
#pragma unroll
    for (int c = 0; c < GC; ++c) acc[c] = 0.f;

#pragma unroll
    for (int p = 0; p < PP; ++p) {
        const int kx = p / KK, ky = p % KK;
        float ox = offp[(2*p  )*HWSZ];
        float oy = offp[(2*p+1)*HWSZ];
        float wp = wgtp[p*HWSZ] * khr[kx] * kvr[ky];

        float ux = (float)(x + kx - 1) + ox;
        float uy = (float)(y + ky - 1) + oy;
        float fx = floorf(ux), fy = floorf(uy);
        float wx = ux - fx,    wy = uy - fy;
        int x0 = (int)fx, y0 = (int)fy;
        int x1 = x0 + 1,  y1 = y0 + 1;

        bool vx0 = (unsigned)x0 < (unsigned)WW;
        bool vx1 = (unsigned)x1 < (unsigned)WW;
        bool vy0 = (unsigned)y0 < (unsigned)HH;
        bool vy1 = (unsigned)y1 < (unsigned)HH;

        float w00 = (1.f-wx)*(1.f-wy)*wp; if (!(vx0 && vy0)) w00 = 0.f;
        float w01 =      wx *(1.f-wy)*wp; if (!(vx1 && vy0)) w01 = 0.f;
        float w10 = (1.f-wx)*     wy *wp; if (!(vx0 && vy1)) w10 = 0.f;
        float w11 =      wx *     wy *wp; if (!(vx1 && vy1)) w11 = 0.f;

        int x0c = min(max(x0, 0), WW-1), x1c = min(max(x1, 0), WW-1);
        int y0c = min(max(y0, 0), HH-1), y1c = min(max(y1, 0), HH-1);
        int i00 = y0c*WW + x0c;
        int i01 = y0c*WW + x1c;
        int i10 = y1c*WW + x0c;
        int i11 = y1c*WW + x1c;

#pragma unroll
        for (int c = 0; c < GC; ++c) {
            const float* pl = imgp + c*HWSZ;
            acc[c] = fmaf(w00, pl[i00], acc[c]);
            acc[c] = fmaf(w01, pl[i01], acc[c]);
            acc[c] = fmaf(w10, pl[i10], acc[c]);
            acc[c] = fmaf(w11, pl[i11], acc[c]);
        }
    }

    float* outp = out + (size_t)(b*CC + g*GC) * HWSZ + pix;
#pragma unroll
    for (int c = 0; c < GC; ++c) outp[c*HWSZ] = acc[c];
}

extern "C" void kernel_launch(void* const* d_in, const int* in_sizes, int n_in,
                              void* d_out, int out_size, void* d_ws, size_t ws_size,
                              hipStream_t stream) {
    const float* img = (const float*)d_in[0];
    const float* kv  = (const float*)d_in[1];
    const float* kh  = (const float*)d_in[2];
    const float* off = (const float*)d_in[3];
    const float* wgt = (const float*)d_in[4];
    float* out = (float*)d_out;

    dim3 grid(NB*GG*HH);   // 2048 blocks
    dim3 block(WW);        // 256 threads = one output row
    misc_filter_kernel<<<grid, block, 0, stream>>>(img, kv, kh, off, wgt, out);
}

// Round 2
// 199.426 us; speedup vs baseline: 1.0298x; 1.0298x over previous
//
#include <hip/hip_runtime.h>

#define HH 256
#define WW 256
#define HWSZ (HH*WW)
#define CC 64
#define GG 4
#define GC 16
#define HC 8          // channels per thread (half of a group)
#define KK 3
#define PP 9
#define NB 2
#define NBLK (NB*GG*2*HH)   // 4096 blocks

__global__ __launch_bounds__(256, 4) void misc_filter_kernel(
    const float* __restrict__ img,
    const float* __restrict__ kv,
    const float* __restrict__ kh,
    const float* __restrict__ off,
    const float* __restrict__ wgt,
    float* __restrict__ out)
{
    // XCD swizzle: 4096 blocks, 8 XCDs -> each XCD a contiguous 512-block chunk
    // = one (b,g) pair (both channel halves): 4MB planar img slice fits one L2.
    int phys = blockIdx.x;
    int logical = (phys & 7) * (NBLK / 8) + (phys >> 3);
    int y  = logical & (HH - 1);
    int t  = logical >> 8;            // [0, 16)
    int hc = t & 1;                   // channel half
    int g  = (t >> 1) & (GG - 1);
    int b  = t >> 3;
    int x  = threadIdx.x;

    const float* imgp = img + (size_t)(b*CC + g*GC + hc*HC) * HWSZ;
    int pix = y*WW + x;
    const float* offp = off + (size_t)(b*GG*PP*2 + g*PP*2) * HWSZ + pix;
    const float* wgtp = wgt + (size_t)(b*GG*PP   + g*PP  ) * HWSZ + pix;
    const float* khp  = kh  + (size_t)(b*GG*KK   + g*KK  ) * HWSZ + pix;
    const float* kvp  = kv  + (size_t)(b*KK) * HWSZ + pix;

    // ---- Phase A: hoist ALL coalesced parameter loads (issued back-to-back) ----
    float oxr[PP], oyr[PP], wpr[PP];
#pragma unroll
    for (int p = 0; p < PP; ++p) {
        oxr[p] = offp[(2*p  )*HWSZ];
        oyr[p] = offp[(2*p+1)*HWSZ];
        wpr[p] = wgtp[p*HWSZ];
    }
    float khr[KK], kvr[KK];
#pragma unroll
    for (int i = 0; i < KK; ++i) { khr[i] = khp[i*HWSZ]; kvr[i] = kvp[i*HWSZ]; }

    float acc[HC];
#pragma unroll
    for (int c = 0; c < HC; ++c) acc[c] = 0.f;

    // ---- Phase B: per tap, issue all 32 gathers, then all 32 FMAs ----
#pragma unroll
    for (int p = 0; p < PP; ++p) {
        const int kx = p / KK, ky = p % KK;
        float wp = wpr[p] * khr[kx] * kvr[ky];

        float ux = (float)(x + kx - 1) + oxr[p];
        float uy = (float)(y + ky - 1) + oyr[p];
        float fx = floorf(ux), fy = floorf(uy);
        float wx = ux - fx,    wy = uy - fy;
        int x0 = (int)fx, y0 = (int)fy;
        int x1 = x0 + 1,  y1 = y0 + 1;

        bool vx0 = (unsigned)x0 < (unsigned)WW;
        bool vx1 = (unsigned)x1 < (unsigned)WW;
        bool vy0 = (unsigned)y0 < (unsigned)HH;
        bool vy1 = (unsigned)y1 < (unsigned)HH;

        float w00 = (1.f-wx)*(1.f-wy)*wp; if (!(vx0 && vy0)) w00 = 0.f;
        float w01 =      wx *(1.f-wy)*wp; if (!(vx1 && vy0)) w01 = 0.f;
        float w10 = (1.f-wx)*     wy *wp; if (!(vx0 && vy1)) w10 = 0.f;
        float w11 =      wx *     wy *wp; if (!(vx1 && vy1)) w11 = 0.f;

        int x0c = min(max(x0, 0), WW-1), x1c = min(max(x1, 0), WW-1);
        int y0c = min(max(y0, 0), HH-1), y1c = min(max(y1, 0), HH-1);
        int i00 = y0c*WW + x0c;
        int i01 = y0c*WW + x1c;
        int i10 = y1c*WW + x0c;
        int i11 = y1c*WW + x1c;

        float v00[HC], v01[HC], v10[HC], v11[HC];
#pragma unroll
        for (int c = 0; c < HC; ++c) {
            const float* pl = imgp + c*HWSZ;
            v00[c] = pl[i00];
            v01[c] = pl[i01];
            v10[c] = pl[i10];
            v11[c] = pl[i11];
        }
#pragma unroll
        for (int c = 0; c < HC; ++c) {
            acc[c] = fmaf(w00, v00[c], acc[c]);
            acc[c] = fmaf(w01, v01[c], acc[c]);
            acc[c] = fmaf(w10, v10[c], acc[c]);
            acc[c] = fmaf(w11, v11[c], acc[c]);
        }
    }

    float* outp = out + (size_t)(b*CC + g*GC + hc*HC) * HWSZ + pix;
#pragma unroll
    for (int c = 0; c < HC; ++c) outp[c*HWSZ] = acc[c];
}

extern "C" void kernel_launch(void* const* d_in, const int* in_sizes, int n_in,
                              void* d_out, int out_size, void* d_ws, size_t ws_size,
                              hipStream_t stream) {
    const float* img = (const float*)d_in[0];
    const float* kv  = (const float*)d_in[1];
    const float* kh  = (const float*)d_in[2];
    const float* off = (const float*)d_in[3];
    const float* wgt = (const float*)d_in[4];
    float* out = (float*)d_out;

    dim3 grid(NBLK);
    dim3 block(WW);
    misc_filter_kernel<<<grid, block, 0, stream>>>(img, kv, kh, off, wgt, out);
}

// Round 3
// 190.344 us; speedup vs baseline: 1.0790x; 1.0477x over previous
//
#include <hip/hip_runtime.h>

#define HH 256
#define WW 256
#define HWSZ (HH*WW)
#define CC 64
#define GG 4
#define GC 16
#define KK 3
#define PP 9
#define NB 2
#define NBG (NB*GG)          // 8 (b,g) slices
#define NBLK (NBG*HH)        // 2048 blocks

// ---------- Kernel 1: planar -> channels-last repack (per (b,g): [y][x][16]) ----------
__global__ __launch_bounds__(256) void repack_kernel(
    const float* __restrict__ img, float* __restrict__ pk)
{
    int bid = blockIdx.x;
    int y  = bid & (HH - 1);
    int bg = bid >> 8;               // 0..7
    int g  = bg & (GG - 1);
    int b  = bg >> 2;
    int x  = threadIdx.x;

    const float* src = img + (size_t)(b*CC + g*GC) * HWSZ + y*WW + x;
    float v[GC];
#pragma unroll
    for (int c = 0; c < GC; ++c) v[c] = src[c*HWSZ];

    float4* dst = (float4*)(pk + ((size_t)bg*HWSZ + y*WW + x) * GC);
#pragma unroll
    for (int q = 0; q < 4; ++q)
        dst[q] = make_float4(v[4*q], v[4*q+1], v[4*q+2], v[4*q+3]);
}

// ---------- Kernel 2: main filter, gathers 64B pixel-groups ----------
__global__ __launch_bounds__(256, 4) void misc_filter_packed(
    const float* __restrict__ pk,
    const float* __restrict__ kv,
    const float* __restrict__ kh,
    const float* __restrict__ off,
    const float* __restrict__ wgt,
    float* __restrict__ out)
{
    // XCD swizzle: 2048 blocks / 8 XCDs -> each XCD one (b,g); its 4MB packed
    // slice fits exactly in that XCD's L2.
    int phys = blockIdx.x;
    int logical = (phys & 7) * (NBLK / 8) + (phys >> 3);
    int y  = logical & (HH - 1);
    int bg = logical >> 8;
    int g  = bg & (GG - 1);
    int b  = bg >> 2;
    int x  = threadIdx.x;

    const float* pkp = pk + (size_t)bg * HWSZ * GC;
    int pix = y*WW + x;
    const float* offp = off + (size_t)(b*GG*PP*2 + g*PP*2) * HWSZ + pix;
    const float* wgtp = wgt + (size_t)(b*GG*PP   + g*PP  ) * HWSZ + pix;
    const float* khp  = kh  + (size_t)(b*GG*KK   + g*KK  ) * HWSZ + pix;
    const float* kvp  = kv  + (size_t)(b*KK) * HWSZ + pix;

    // hoist all coalesced parameter loads
    float oxr[PP], oyr[PP], wpr[PP];
#pragma unroll
    for (int p = 0; p < PP; ++p) {
        oxr[p] = offp[(2*p  )*HWSZ];
        oyr[p] = offp[(2*p+1)*HWSZ];
        wpr[p] = wgtp[p*HWSZ];
    }
    float khr[KK], kvr[KK];
#pragma unroll
    for (int i = 0; i < KK; ++i) { khr[i] = khp[i*HWSZ]; kvr[i] = kvp[i*HWSZ]; }

    float acc[GC];
#pragma unroll
    for (int c = 0; c < GC; ++c) acc[c] = 0.f;

#pragma unroll
    for (int p = 0; p < PP; ++p) {
        const int kx = p / KK, ky = p % KK;
        float wp = wpr[p] * khr[kx] * kvr[ky];

        float ux = (float)(x + kx - 1) + oxr[p];
        float uy = (float)(y + ky - 1) + oyr[p];
        float fx = floorf(ux), fy = floorf(uy);
        float wx = ux - fx,    wy = uy - fy;
        int x0 = (int)fx, y0 = (int)fy;
        int x1 = x0 + 1,  y1 = y0 + 1;

        bool vx0 = (unsigned)x0 < (unsigned)WW;
        bool vx1 = (unsigned)x1 < (unsigned)WW;
        bool vy0 = (unsigned)y0 < (unsigned)HH;
        bool vy1 = (unsigned)y1 < (unsigned)HH;

        float w00 = (1.f-wx)*(1.f-wy)*wp; if (!(vx0 && vy0)) w00 = 0.f;
        float w01 =      wx *(1.f-wy)*wp; if (!(vx1 && vy0)) w01 = 0.f;
        float w10 = (1.f-wx)*     wy *wp; if (!(vx0 && vy1)) w10 = 0.f;
        float w11 =      wx *     wy *wp; if (!(vx1 && vy1)) w11 = 0.f;

        int x0c = min(max(x0, 0), WW-1), x1c = min(max(x1, 0), WW-1);
        int y0c = min(max(y0, 0), HH-1), y1c = min(max(y1, 0), HH-1);

        const float4* p00 = (const float4*)(pkp + (size_t)(y0c*WW + x0c) * GC);
        const float4* p01 = (const float4*)(pkp + (size_t)(y0c*WW + x1c) * GC);
        const float4* p10 = (const float4*)(pkp + (size_t)(y1c*WW + x0c) * GC);
        const float4* p11 = (const float4*)(pkp + (size_t)(y1c*WW + x1c) * GC);

        float4 v00[4], v01[4], v10[4], v11[4];
#pragma unroll
        for (int q = 0; q < 4; ++q) v00[q] = p00[q];
#pragma unroll
        for (int q = 0; q < 4; ++q) v01[q] = p01[q];
#pragma unroll
        for (int q = 0; q < 4; ++q) v10[q] = p10[q];
#pragma unroll
        for (int q = 0; q < 4; ++q) v11[q] = p11[q];

#pragma unroll
        for (int q = 0; q < 4; ++q) {
            acc[4*q+0] = fmaf(w00, v00[q].x, acc[4*q+0]);
            acc[4*q+1] = fmaf(w00, v00[q].y, acc[4*q+1]);
            acc[4*q+2] = fmaf(w00, v00[q].z, acc[4*q+2]);
            acc[4*q+3] = fmaf(w00, v00[q].w, acc[4*q+3]);
            acc[4*q+0] = fmaf(w01, v01[q].x, acc[4*q+0]);
            acc[4*q+1] = fmaf(w01, v01[q].y, acc[4*q+1]);
            acc[4*q+2] = fmaf(w01, v01[q].z, acc[4*q+2]);
            acc[4*q+3] = fmaf(w01, v01[q].w, acc[4*q+3]);
            acc[4*q+0] = fmaf(w10, v10[q].x, acc[4*q+0]);
            acc[4*q+1] = fmaf(w10, v10[q].y, acc[4*q+1]);
            acc[4*q+2] = fmaf(w10, v10[q].z, acc[4*q+2]);
            acc[4*q+3] = fmaf(w10, v10[q].w, acc[4*q+3]);
            acc[4*q+0] = fmaf(w11, v11[q].x, acc[4*q+0]);
            acc[4*q+1] = fmaf(w11, v11[q].y, acc[4*q+1]);
            acc[4*q+2] = fmaf(w11, v11[q].z, acc[4*q+2]);
            acc[4*q+3] = fmaf(w11, v11[q].w, acc[4*q+3]);
        }
    }

    float* outp = out + (size_t)(b*CC + g*GC) * HWSZ + pix;
#pragma unroll
    for (int c = 0; c < GC; ++c) outp[c*HWSZ] = acc[c];
}

// ---------- Fallback: direct planar kernel (if ws too small) ----------
__global__ __launch_bounds__(256) void misc_filter_direct(
    const float* __restrict__ img,
    const float* __restrict__ kv,
    const float* __restrict__ kh,
    const float* __restrict__ off,
    const float* __restrict__ wgt,
    float* __restrict__ out)
{
    int phys = blockIdx.x;
    int logical = (phys & 7) * (NBLK / 8) + (phys >> 3);
    int y  = logical & (HH - 1);
    int bg = logical >> 8;
    int g  = bg & (GG - 1);
    int b  = bg >> 2;
    int x  = threadIdx.x;

    const float* imgp = img + (size_t)(b*CC + g*GC) * HWSZ;
    int pix = y*WW + x;
    const float* offp = off + (size_t)(b*GG*PP*2 + g*PP*2) * HWSZ + pix;
    const float* wgtp = wgt + (size_t)(b*GG*PP   + g*PP  ) * HWSZ + pix;
    const float* khp  = kh  + (size_t)(b*GG*KK   + g*KK  ) * HWSZ + pix;
    const float* kvp  = kv  + (size_t)(b*KK) * HWSZ + pix;

    float khr[KK], kvr[KK];
#pragma unroll
    for (int i = 0; i < KK; ++i) { khr[i] = khp[i*HWSZ]; kvr[i] = kvp[i*HWSZ]; }
    float acc[GC];
#pragma unroll
    for (int c = 0; c < GC; ++c) acc[c] = 0.f;

#pragma unroll
    for (int p = 0; p < PP; ++p) {
        const int kx = p / KK, ky = p % KK;
        float ox = offp[(2*p  )*HWSZ];
        float oy = offp[(2*p+1)*HWSZ];
        float wp = wgtp[p*HWSZ] * khr[kx] * kvr[ky];
        float ux = (float)(x + kx - 1) + ox;
        float uy = (float)(y + ky - 1) + oy;
        float fx = floorf(ux), fy = floorf(uy);
        float wx = ux - fx,    wy = uy - fy;
        int x0 = (int)fx, y0 = (int)fy;
        int x1 = x0 + 1,  y1 = y0 + 1;
        bool vx0 = (unsigned)x0 < (unsigned)WW;
        bool vx1 = (unsigned)x1 < (unsigned)WW;
        bool vy0 = (unsigned)y0 < (unsigned)HH;
        bool vy1 = (unsigned)y1 < (unsigned)HH;
        float w00 = (1.f-wx)*(1.f-wy)*wp; if (!(vx0 && vy0)) w00 = 0.f;
        float w01 =      wx *(1.f-wy)*wp; if (!(vx1 && vy0)) w01 = 0.f;
        float w10 = (1.f-wx)*     wy *wp; if (!(vx0 && vy1)) w10 = 0.f;
        float w11 =      wx *     wy *wp; if (!(vx1 && vy1)) w11 = 0.f;
        int x0c = min(max(x0, 0), WW-1), x1c = min(max(x1, 0), WW-1);
        int y0c = min(max(y0, 0), HH-1), y1c = min(max(y1, 0), HH-1);
        int i00 = y0c*WW + x0c, i01 = y0c*WW + x1c;
        int i10 = y1c*WW + x0c, i11 = y1c*WW + x1c;
#pragma unroll
        for (int c = 0; c < GC; ++c) {
            const float* pl = imgp + c*HWSZ;
            acc[c] = fmaf(w00, pl[i00], acc[c]);
            acc[c] = fmaf(w01, pl[i01], acc[c]);
            acc[c] = fmaf(w10, pl[i10], acc[c]);
            acc[c] = fmaf(w11, pl[i11], acc[c]);
        }
    }
    float* outp = out + (size_t)(b*CC + g*GC) * HWSZ + pix;
#pragma unroll
    for (int c = 0; c < GC; ++c) outp[c*HWSZ] = acc[c];
}

extern "C" void kernel_launch(void* const* d_in, const int* in_sizes, int n_in,
                              void* d_out, int out_size, void* d_ws, size_t ws_size,
                              hipStream_t stream) {
    const float* img = (const float*)d_in[0];
    const float* kv  = (const float*)d_in[1];
    const float* kh  = (const float*)d_in[2];
    const float* off = (const float*)d_in[3];
    const float* wgt = (const float*)d_in[4];
    float* out = (float*)d_out;

    const size_t need = (size_t)NBG * HWSZ * GC * sizeof(float);  // 33.5 MB
    if (ws_size >= need) {
        float* pk = (float*)d_ws;
        repack_kernel<<<dim3(NBLK), dim3(WW), 0, stream>>>(img, pk);
        misc_filter_packed<<<dim3(NBLK), dim3(WW), 0, stream>>>(pk, kv, kh, off, wgt, out);
    } else {
        misc_filter_direct<<<dim3(NBLK), dim3(WW), 0, stream>>>(img, kv, kh, off, wgt, out);
    }
}

// Round 4
// 80.103 us; speedup vs baseline: 2.5638x; 2.3762x over previous
//
#include <hip/hip_runtime.h>

#define HH 256
#define WW 256
#define HWSZ (HH*WW)
#define CC 64
#define GG 4
#define GC 16
#define KK 3
#define PP 9
#define NB 2
#define NBG (NB*GG)            // 8 (b,g) slices
#define NBLK_RP (NBG*HH)       // 2048 repack blocks
#define NBLK_MAIN (NBG*1024)   // 8192 main blocks (64 pixels x 4 lanes each)

// ---------- Kernel 1: planar -> channels-last repack (per (b,g): [y][x][16]) ----------
__global__ __launch_bounds__(256) void repack_kernel(
    const float* __restrict__ img, float* __restrict__ pk)
{
    int bid = blockIdx.x;
    int y  = bid & (HH - 1);
    int bg = bid >> 8;
    int g  = bg & (GG - 1);
    int b  = bg >> 2;
    int x  = threadIdx.x;

    const float* src = img + (size_t)(b*CC + g*GC) * HWSZ + y*WW + x;
    float v[GC];
#pragma unroll
    for (int c = 0; c < GC; ++c) v[c] = src[c*HWSZ];

    float4* dst = (float4*)(pk + ((size_t)bg*HWSZ + y*WW + x) * GC);
#pragma unroll
    for (int q = 0; q < 4; ++q)
        dst[q] = make_float4(v[4*q], v[4*q+1], v[4*q+2], v[4*q+3]);
}

// ---------- Kernel 2: cooperative main filter ----------
// 4 lanes per pixel; lane q handles channels [4q, 4q+4). Every gather
// instruction: 16 pixel-groups x full 64B line = 16 lines / wave (minimum).
__global__ __launch_bounds__(256, 4) void misc_filter_coop(
    const float* __restrict__ pk,
    const float* __restrict__ kv,
    const float* __restrict__ kh,
    const float* __restrict__ off,
    const float* __restrict__ wgt,
    float* __restrict__ out)
{
    // XCD swizzle: 8192 blocks / 8 XCDs -> each XCD exactly one (b,g);
    // its 4MB packed slice lives in that XCD's L2.
    int phys = blockIdx.x;
    int logical = (phys & 7) * (NBLK_MAIN / 8) + (phys >> 3);
    int bg  = logical >> 10;          // 1024 blocks per (b,g)
    int blk = logical & 1023;
    int g   = bg & (GG - 1);
    int b   = bg >> 2;

    int t  = threadIdx.x;
    int q  = t & 3;                   // float4 quadrant / channel quad
    int pi = t >> 2;                  // pixel within block [0,64)
    int pixel = blk * 64 + pi;        // [0, 65536)
    int y = pixel >> 8;
    int x = pixel & (WW - 1);

    const float* pkp = pk + (size_t)bg * HWSZ * GC;
    const float* offp = off + (size_t)(b*GG*PP*2 + g*PP*2) * HWSZ + pixel;
    const float* wgtp = wgt + (size_t)(b*GG*PP   + g*PP  ) * HWSZ + pixel;
    const float* khp  = kh  + (size_t)(b*GG*KK   + g*KK  ) * HWSZ + pixel;
    const float* kvp  = kv  + (size_t)(b*KK) * HWSZ + pixel;

    // hoisted parameter loads (4 lanes/pixel read the same address: 1-2 lines/instr)
    float oxr[PP], oyr[PP], wpr[PP];
#pragma unroll
    for (int p = 0; p < PP; ++p) {
        oxr[p] = offp[(2*p  )*HWSZ];
        oyr[p] = offp[(2*p+1)*HWSZ];
        wpr[p] = wgtp[p*HWSZ];
    }
    float khr[KK], kvr[KK];
#pragma unroll
    for (int i = 0; i < KK; ++i) { khr[i] = khp[i*HWSZ]; kvr[i] = kvp[i*HWSZ]; }

    float acc0 = 0.f, acc1 = 0.f, acc2 = 0.f, acc3 = 0.f;
    const int qoff = q * 4;           // float offset of this lane's quadrant

#pragma unroll
    for (int p = 0; p < PP; ++p) {
        const int kx = p / KK, ky = p % KK;
        float wp = wpr[p] * khr[kx] * kvr[ky];

        float ux = (float)(x + kx - 1) + oxr[p];
        float uy = (float)(y + ky - 1) + oyr[p];
        float fx = floorf(ux), fy = floorf(uy);
        float wx = ux - fx,    wy = uy - fy;
        int x0 = (int)fx, y0 = (int)fy;
        int x1 = x0 + 1,  y1 = y0 + 1;

        bool vx0 = (unsigned)x0 < (unsigned)WW;
        bool vx1 = (unsigned)x1 < (unsigned)WW;
        bool vy0 = (unsigned)y0 < (unsigned)HH;
        bool vy1 = (unsigned)y1 < (unsigned)HH;

        float w00 = (1.f-wx)*(1.f-wy)*wp; if (!(vx0 && vy0)) w00 = 0.f;
        float w01 =      wx *(1.f-wy)*wp; if (!(vx1 && vy0)) w01 = 0.f;
        float w10 = (1.f-wx)*     wy *wp; if (!(vx0 && vy1)) w10 = 0.f;
        float w11 =      wx *     wy *wp; if (!(vx1 && vy1)) w11 = 0.f;

        int x0c = min(max(x0, 0), WW-1), x1c = min(max(x1, 0), WW-1);
        int y0c = min(max(y0, 0), HH-1), y1c = min(max(y1, 0), HH-1);

        float4 v00 = *(const float4*)(pkp + (y0c*WW + x0c)*GC + qoff);
        float4 v01 = *(const float4*)(pkp + (y0c*WW + x1c)*GC + qoff);
        float4 v10 = *(const float4*)(pkp + (y1c*WW + x0c)*GC + qoff);
        float4 v11 = *(const float4*)(pkp + (y1c*WW + x1c)*GC + qoff);

        acc0 = fmaf(w00, v00.x, acc0); acc1 = fmaf(w00, v00.y, acc1);
        acc2 = fmaf(w00, v00.z, acc2); acc3 = fmaf(w00, v00.w, acc3);
        acc0 = fmaf(w01, v01.x, acc0); acc1 = fmaf(w01, v01.y, acc1);
        acc2 = fmaf(w01, v01.z, acc2); acc3 = fmaf(w01, v01.w, acc3);
        acc0 = fmaf(w10, v10.x, acc0); acc1 = fmaf(w10, v10.y, acc1);
        acc2 = fmaf(w10, v10.z, acc2); acc3 = fmaf(w10, v10.w, acc3);
        acc0 = fmaf(w11, v11.x, acc0); acc1 = fmaf(w11, v11.y, acc1);
        acc2 = fmaf(w11, v11.z, acc2); acc3 = fmaf(w11, v11.w, acc3);
    }

    float* outp = out + (size_t)(b*CC + g*GC + q*4) * HWSZ + pixel;
    outp[0*HWSZ] = acc0;
    outp[1*HWSZ] = acc1;
    outp[2*HWSZ] = acc2;
    outp[3*HWSZ] = acc3;
}

// ---------- Fallback: direct planar kernel (if ws too small) ----------
__global__ __launch_bounds__(256) void misc_filter_direct(
    const float* __restrict__ img,
    const float* __restrict__ kv,
    const float* __restrict__ kh,
    const float* __restrict__ off,
    const float* __restrict__ wgt,
    float* __restrict__ out)
{
    int phys = blockIdx.x;
    int logical = (phys & 7) * (NBLK_RP / 8) + (phys >> 3);
    int y  = logical & (HH - 1);
    int bg = logical >> 8;
    int g  = bg & (GG - 1);
    int b  = bg >> 2;
    int x  = threadIdx.x;

    const float* imgp = img + (size_t)(b*CC + g*GC) * HWSZ;
    int pix = y*WW + x;
    const float* offp = off + (size_t)(b*GG*PP*2 + g*PP*2) * HWSZ + pix;
    const float* wgtp = wgt + (size_t)(b*GG*PP   + g*PP  ) * HWSZ + pix;
    const float* khp  = kh  + (size_t)(b*GG*KK   + g*KK  ) * HWSZ + pix;
    const float* kvp  = kv  + (size_t)(b*KK) * HWSZ + pix;

    float khr[KK], kvr[KK];
#pragma unroll
    for (int i = 0; i < KK; ++i) { khr[i] = khp[i*HWSZ]; kvr[i] = kvp[i*HWSZ]; }
    float acc[GC];
#pragma unroll
    for (int c = 0; c < GC; ++c) acc[c] = 0.f;

#pragma unroll
    for (int p = 0; p < PP; ++p) {
        const int kx = p / KK, ky = p % KK;
        float ox = offp[(2*p  )*HWSZ];
        float oy = offp[(2*p+1)*HWSZ];
        float wp = wgtp[p*HWSZ] * khr[kx] * kvr[ky];
        float ux = (float)(x + kx - 1) + ox;
        float uy = (float)(y + ky - 1) + oy;
        float fx = floorf(ux), fy = floorf(uy);
        float wx = ux - fx,    wy = uy - fy;
        int x0 = (int)fx, y0 = (int)fy;
        int x1 = x0 + 1,  y1 = y0 + 1;
        bool vx0 = (unsigned)x0 < (unsigned)WW;
        bool vx1 = (unsigned)x1 < (unsigned)WW;
        bool vy0 = (unsigned)y0 < (unsigned)HH;
        bool vy1 = (unsigned)y1 < (unsigned)HH;
        float w00 = (1.f-wx)*(1.f-wy)*wp; if (!(vx0 && vy0)) w00 = 0.f;
        float w01 =      wx *(1.f-wy)*wp; if (!(vx1 && vy0)) w01 = 0.f;
        float w10 = (1.f-wx)*     wy *wp; if (!(vx0 && vy1)) w10 = 0.f;
        float w11 =      wx *     wy *wp; if (!(vx1 && vy1)) w11 = 0.f;
        int x0c = min(max(x0, 0), WW-1), x1c = min(max(x1, 0), WW-1);
        int y0c = min(max(y0, 0), HH-1), y1c = min(max(y1, 0), HH-1);
        int i00 = y0c*WW + x0c, i01 = y0c*WW + x1c;
        int i10 = y1c*WW + x0c, i11 = y1c*WW + x1c;
#pragma unroll
        for (int c = 0; c < GC; ++c) {
            const float* pl = imgp + c*HWSZ;
            acc[c] = fmaf(w00, pl[i00], acc[c]);
            acc[c] = fmaf(w01, pl[i01], acc[c]);
            acc[c] = fmaf(w10, pl[i10], acc[c]);
            acc[c] = fmaf(w11, pl[i11], acc[c]);
        }
    }
    float* outp = out + (size_t)(b*CC + g*GC) * HWSZ + pix;
#pragma unroll
    for (int c = 0; c < GC; ++c) outp[c*HWSZ] = acc[c];
}

extern "C" void kernel_launch(void* const* d_in, const int* in_sizes, int n_in,
                              void* d_out, int out_size, void* d_ws, size_t ws_size,
                              hipStream_t stream) {
    const float* img = (const float*)d_in[0];
    const float* kv  = (const float*)d_in[1];
    const float* kh  = (const float*)d_in[2];
    const float* off = (const float*)d_in[3];
    const float* wgt = (const float*)d_in[4];
    float* out = (float*)d_out;

    const size_t need = (size_t)NBG * HWSZ * GC * sizeof(float);  // 33.5 MB
    if (ws_size >= need) {
        float* pk = (float*)d_ws;
        repack_kernel<<<dim3(NBLK_RP), dim3(WW), 0, stream>>>(img, pk);
        misc_filter_coop<<<dim3(NBLK_MAIN), dim3(256), 0, stream>>>(pk, kv, kh, off, wgt, out);
    } else {
        misc_filter_direct<<<dim3(NBLK_RP), dim3(WW), 0, stream>>>(img, kv, kh, off, wgt, out);
    }
}

// Round 5
// 75.750 us; speedup vs baseline: 2.7112x; 1.0575x over previous
//
#include <hip/hip_runtime.h>

#define HH 256
#define WW 256
#define HWSZ (HH*WW)
#define CC 64
#define GG 4
#define GC 16
#define KK 3
#define PP 9
#define NB 2
#define NBG (NB*GG)            // 8 (b,g) slices
#define NBLK_RP (NBG*HH)       // 2048 repack blocks
#define NBLK_MAIN (NBG*1024)   // 8192 main blocks (64 pixels x 4 lanes each)

// ---------- Kernel 1: planar -> channels-last repack (per (b,g): [y][x][16]) ----------
__global__ __launch_bounds__(256) void repack_kernel(
    const float* __restrict__ img, float* __restrict__ pk)
{
    int bid = blockIdx.x;
    int y  = bid & (HH - 1);
    int bg = bid >> 8;
    int g  = bg & (GG - 1);
    int b  = bg >> 2;
    int x  = threadIdx.x;

    const float* src = img + (size_t)(b*CC + g*GC) * HWSZ + y*WW + x;
    float v[GC];
#pragma unroll
    for (int c = 0; c < GC; ++c) v[c] = src[c*HWSZ];

    float4* dst = (float4*)(pk + ((size_t)bg*HWSZ + y*WW + x) * GC);
#pragma unroll
    for (int q = 0; q < 4; ++q)
        dst[q] = make_float4(v[4*q], v[4*q+1], v[4*q+2], v[4*q+3]);
}

// ---------- Kernel 2: cooperative main filter, 2-deep software pipeline ----------
// 4 lanes per pixel; lane q handles channels [4q,4q+4). Gather instr = 16 full
// 64B lines/wave (minimum). Pipeline: MATH(p)/LOAD(p) run 2 taps ahead of
// FMA(p-2) so 8-12 loads stay in flight per wave.
__global__ __launch_bounds__(256, 4) void misc_filter_coop(
    const float* __restrict__ pk,
    const float* __restrict__ kv,
    const float* __restrict__ kh,
    const float* __restrict__ off,
    const float* __restrict__ wgt,
    float* __restrict__ out)
{
    // XCD swizzle: 8192 blocks / 8 XCDs -> each XCD exactly one (b,g);
    // its 4MB packed slice lives in that XCD's L2.
    int phys = blockIdx.x;
    int logical = (phys & 7) * (NBLK_MAIN / 8) + (phys >> 3);
    int bg  = logical >> 10;          // 1024 blocks per (b,g)
    int blk = logical & 1023;
    int g   = bg & (GG - 1);
    int b   = bg >> 2;

    int t  = threadIdx.x;
    int q  = t & 3;                   // channel quad
    int pi = t >> 2;                  // pixel within block [0,64)
    int pixel = blk * 64 + pi;
    int y = pixel >> 8;
    int x = pixel & (WW - 1);

    const char* pkb = (const char*)(pk + (size_t)bg * HWSZ * GC);
    const float* offp = off + (size_t)(b*GG*PP*2 + g*PP*2) * HWSZ + pixel;
    const float* wgtp = wgt + (size_t)(b*GG*PP   + g*PP  ) * HWSZ + pixel;
    const float* khp  = kh  + (size_t)(b*GG*KK   + g*KK  ) * HWSZ + pixel;
    const float* kvp  = kv  + (size_t)(b*KK) * HWSZ + pixel;

    // hoisted parameter loads
    float oxr[PP], oyr[PP], wpr[PP];
#pragma unroll
    for (int p = 0; p < PP; ++p) {
        oxr[p] = offp[(2*p  )*HWSZ];
        oyr[p] = offp[(2*p+1)*HWSZ];
        wpr[p] = wgtp[p*HWSZ];
    }
    float khr[KK], kvr[KK];
#pragma unroll
    for (int i = 0; i < KK; ++i) { khr[i] = khp[i*HWSZ]; kvr[i] = kvp[i*HWSZ]; }

    float acc0 = 0.f, acc1 = 0.f, acc2 = 0.f, acc3 = 0.f;
    const unsigned qoffb = (unsigned)q * 16u;   // byte offset of this lane's quadrant

    float    w4[PP][4];     // folded corner weights
    unsigned ob[PP][4];     // byte offsets into packed slice
    float4   vv[PP][4];     // loaded corner vectors

#define TAP_MATH(p) do {                                                        \
    const int kx_ = (p) / KK, ky_ = (p) % KK;                                   \
    float wp_ = wpr[p] * khr[kx_] * kvr[ky_];                                   \
    float ux_ = (float)(x + kx_ - 1) + oxr[p];                                  \
    float uy_ = (float)(y + ky_ - 1) + oyr[p];                                  \
    float fx_ = floorf(ux_), fy_ = floorf(uy_);                                 \
    float wx_ = ux_ - fx_,   wy_ = uy_ - fy_;                                   \
    int x0_ = (int)fx_, y0_ = (int)fy_;                                         \
    int x1_ = x0_ + 1,  y1_ = y0_ + 1;                                          \
    bool vx0_ = (unsigned)x0_ < (unsigned)WW;                                   \
    bool vx1_ = (unsigned)x1_ < (unsigned)WW;                                   \
    bool vy0_ = (unsigned)y0_ < (unsigned)HH;                                   \
    bool vy1_ = (unsigned)y1_ < (unsigned)HH;                                   \
    float w00_ = (1.f-wx_)*(1.f-wy_)*wp_; if (!(vx0_ && vy0_)) w00_ = 0.f;      \
    float w01_ =      wx_ *(1.f-wy_)*wp_; if (!(vx1_ && vy0_)) w01_ = 0.f;      \
    float w10_ = (1.f-wx_)*     wy_ *wp_; if (!(vx0_ && vy1_)) w10_ = 0.f;      \
    float w11_ =      wx_ *     wy_ *wp_; if (!(vx1_ && vy1_)) w11_ = 0.f;      \
    int x0c_ = min(max(x0_, 0), WW-1), x1c_ = min(max(x1_, 0), WW-1);           \
    int y0c_ = min(max(y0_, 0), HH-1), y1c_ = min(max(y1_, 0), HH-1);           \
    w4[p][0] = w00_; w4[p][1] = w01_; w4[p][2] = w10_; w4[p][3] = w11_;         \
    ob[p][0] = (unsigned)((y0c_*WW + x0c_)*GC)*4u + qoffb;                      \
    ob[p][1] = (unsigned)((y0c_*WW + x1c_)*GC)*4u + qoffb;                      \
    ob[p][2] = (unsigned)((y1c_*WW + x0c_)*GC)*4u + qoffb;                      \
    ob[p][3] = (unsigned)((y1c_*WW + x1c_)*GC)*4u + qoffb;                      \
} while (0)

#define TAP_LOAD(p) do {                                                        \
    vv[p][0] = *(const float4*)(pkb + ob[p][0]);                                \
    vv[p][1] = *(const float4*)(pkb + ob[p][1]);                                \
    vv[p][2] = *(const float4*)(pkb + ob[p][2]);                                \
    vv[p][3] = *(const float4*)(pkb + ob[p][3]);                                \
} while (0)

#define TAP_FMA(p) do {                                                         \
    acc0 = fmaf(w4[p][0], vv[p][0].x, acc0);                                    \
    acc1 = fmaf(w4[p][0], vv[p][0].y, acc1);                                    \
    acc2 = fmaf(w4[p][0], vv[p][0].z, acc2);                                    \
    acc3 = fmaf(w4[p][0], vv[p][0].w, acc3);                                    \
    acc0 = fmaf(w4[p][1], vv[p][1].x, acc0);                                    \
    acc1 = fmaf(w4[p][1], vv[p][1].y, acc1);                                    \
    acc2 = fmaf(w4[p][1], vv[p][1].z, acc2);                                    \
    acc3 = fmaf(w4[p][1], vv[p][1].w, acc3);                                    \
    acc0 = fmaf(w4[p][2], vv[p][2].x, acc0);                                    \
    acc1 = fmaf(w4[p][2], vv[p][2].y, acc1);                                    \
    acc2 = fmaf(w4[p][2], vv[p][2].z, acc2);                                    \
    acc3 = fmaf(w4[p][2], vv[p][2].w, acc3);                                    \
    acc0 = fmaf(w4[p][3], vv[p][3].x, acc0);                                    \
    acc1 = fmaf(w4[p][3], vv[p][3].y, acc1);                                    \
    acc2 = fmaf(w4[p][3], vv[p][3].z, acc2);                                    \
    acc3 = fmaf(w4[p][3], vv[p][3].w, acc3);                                    \
} while (0)

    TAP_MATH(0); TAP_LOAD(0);
    TAP_MATH(1); TAP_LOAD(1);
#pragma unroll
    for (int p = 2; p < PP; ++p) {
        TAP_MATH(p); TAP_LOAD(p);
        TAP_FMA(p - 2);
    }
    TAP_FMA(PP - 2);
    TAP_FMA(PP - 1);

#undef TAP_MATH
#undef TAP_LOAD
#undef TAP_FMA

    float* outp = out + (size_t)(b*CC + g*GC + q*4) * HWSZ + pixel;
    outp[0*HWSZ] = acc0;
    outp[1*HWSZ] = acc1;
    outp[2*HWSZ] = acc2;
    outp[3*HWSZ] = acc3;
}

// ---------- Fallback: direct planar kernel (if ws too small) ----------
__global__ __launch_bounds__(256) void misc_filter_direct(
    const float* __restrict__ img,
    const float* __restrict__ kv,
    const float* __restrict__ kh,
    const float* __restrict__ off,
    const float* __restrict__ wgt,
    float* __restrict__ out)
{
    int phys = blockIdx.x;
    int logical = (phys & 7) * (NBLK_RP / 8) + (phys >> 3);
    int y  = logical & (HH - 1);
    int bg = logical >> 8;
    int g  = bg & (GG - 1);
    int b  = bg >> 2;
    int x  = threadIdx.x;

    const float* imgp = img + (size_t)(b*CC + g*GC) * HWSZ;
    int pix = y*WW + x;
    const float* offp = off + (size_t)(b*GG*PP*2 + g*PP*2) * HWSZ + pix;
    const float* wgtp = wgt + (size_t)(b*GG*PP   + g*PP  ) * HWSZ + pix;
    const float* khp  = kh  + (size_t)(b*GG*KK   + g*KK  ) * HWSZ + pix;
    const float* kvp  = kv  + (size_t)(b*KK) * HWSZ + pix;

    float khr[KK], kvr[KK];
#pragma unroll
    for (int i = 0; i < KK; ++i) { khr[i] = khp[i*HWSZ]; kvr[i] = kvp[i*HWSZ]; }
    float acc[GC];
#pragma unroll
    for (int c = 0; c < GC; ++c) acc[c] = 0.f;

#pragma unroll
    for (int p = 0; p < PP; ++p) {
        const int kx = p / KK, ky = p % KK;
        float ox = offp[(2*p  )*HWSZ];
        float oy = offp[(2*p+1)*HWSZ];
        float wp = wgtp[p*HWSZ] * khr[kx] * kvr[ky];
        float ux = (float)(x + kx - 1) + ox;
        float uy = (float)(y + ky - 1) + oy;
        float fx = floorf(ux), fy = floorf(uy);
        float wx = ux - fx,    wy = uy - fy;
        int x0 = (int)fx, y0 = (int)fy;
        int x1 = x0 + 1,  y1 = y0 + 1;
        bool vx0 = (unsigned)x0 < (unsigned)WW;
        bool vx1 = (unsigned)x1 < (unsigned)WW;
        bool vy0 = (unsigned)y0 < (unsigned)HH;
        bool vy1 = (unsigned)y1 < (unsigned)HH;
        float w00 = (1.f-wx)*(1.f-wy)*wp; if (!(vx0 && vy0)) w00 = 0.f;
        float w01 =      wx *(1.f-wy)*wp; if (!(vx1 && vy0)) w01 = 0.f;
        float w10 = (1.f-wx)*     wy *wp; if (!(vx0 && vy1)) w10 = 0.f;
        float w11 =      wx *     wy *wp; if (!(vx1 && vy1)) w11 = 0.f;
        int x0c = min(max(x0, 0), WW-1), x1c = min(max(x1, 0), WW-1);
        int y0c = min(max(y0, 0), HH-1), y1c = min(max(y1, 0), HH-1);
        int i00 = y0c*WW + x0c, i01 = y0c*WW + x1c;
        int i10 = y1c*WW + x0c, i11 = y1c*WW + x1c;
#pragma unroll
        for (int c = 0; c < GC; ++c) {
            const float* pl = imgp + c*HWSZ;
            acc[c] = fmaf(w00, pl[i00], acc[c]);
            acc[c] = fmaf(w01, pl[i01], acc[c]);
            acc[c] = fmaf(w10, pl[i10], acc[c]);
            acc[c] = fmaf(w11, pl[i11], acc[c]);
        }
    }
    float* outp = out + (size_t)(b*CC + g*GC) * HWSZ + pix;
#pragma unroll
    for (int c = 0; c < GC; ++c) outp[c*HWSZ] = acc[c];
}

extern "C" void kernel_launch(void* const* d_in, const int* in_sizes, int n_in,
                              void* d_out, int out_size, void* d_ws, size_t ws_size,
                              hipStream_t stream) {
    const float* img = (const float*)d_in[0];
    const float* kv  = (const float*)d_in[1];
    const float* kh  = (const float*)d_in[2];
    const float* off = (const float*)d_in[3];
    const float* wgt = (const float*)d_in[4];
    float* out = (float*)d_out;

    const size_t need = (size_t)NBG * HWSZ * GC * sizeof(float);  // 33.5 MB
    if (ws_size >= need) {
        float* pk = (float*)d_ws;
        repack_kernel<<<dim3(NBLK_RP), dim3(WW), 0, stream>>>(img, pk);
        misc_filter_coop<<<dim3(NBLK_MAIN), dim3(256), 0, stream>>>(pk, kv, kh, off, wgt, out);
    } else {
        misc_filter_direct<<<dim3(NBLK_RP), dim3(WW), 0, stream>>>(img, kv, kh, off, wgt, out);
    }
}

// Round 6
// 72.439 us; speedup vs baseline: 2.8351x; 1.0457x over previous
//
#include <hip/hip_runtime.h>

#define HH 256
#define WW 256
#define HWSZ (HH*WW)
#define CC 64
#define GG 4
#define GC 16
#define KK 3
#define PP 9
#define NB 2
#define NBG (NB*GG)            // 8 (b,g) slices
#define NBLK_RP (NBG*HH)       // 2048 repack blocks
#define NBLK_MAIN (NBG*1024)   // 8192 main blocks (64 pixels x 4 lanes each)

typedef float f32x4 __attribute__((ext_vector_type(4)));

// ---------- Kernel 1: planar -> channels-last repack (per (b,g): [y][x][16]) ----------
__global__ __launch_bounds__(256) void repack_kernel(
    const float* __restrict__ img, float* __restrict__ pk)
{
    int bid = blockIdx.x;
    int y  = bid & (HH - 1);
    int bg = bid >> 8;
    int g  = bg & (GG - 1);
    int b  = bg >> 2;
    int x  = threadIdx.x;

    const float* src = img + (size_t)(b*CC + g*GC) * HWSZ + y*WW + x;
    float v[GC];
#pragma unroll
    for (int c = 0; c < GC; ++c) v[c] = src[c*HWSZ];

    float4* dst = (float4*)(pk + ((size_t)bg*HWSZ + y*WW + x) * GC);
#pragma unroll
    for (int q = 0; q < 4; ++q)
        dst[q] = make_float4(v[4*q], v[4*q+1], v[4*q+2], v[4*q+3]);
}

// ---------- Kernel 2: cooperative filter, asm-load pipeline w/ counted vmcnt ----------
// 4 lanes per pixel; lane q owns channels [4q,4q+4). Each gather instr reads
// 16 full 64B lines (minimum). 3-tap rotating buffer: 8-12 loads in flight,
// counted vmcnt(8) completes exactly the oldest tap — never drains the pipe.
__global__ __launch_bounds__(256, 4) void misc_filter_coop(
    const float* __restrict__ pk,
    const float* __restrict__ kv,
    const float* __restrict__ kh,
    const float* __restrict__ off,
    const float* __restrict__ wgt,
    float* __restrict__ out)
{
    // XCD swizzle: 8192 blocks / 8 XCDs -> each XCD exactly one (b,g);
    // its 4MB packed slice lives in that XCD's L2.
    int phys = blockIdx.x;
    int logical = (phys & 7) * (NBLK_MAIN / 8) + (phys >> 3);
    int bg  = logical >> 10;          // 1024 blocks per (b,g)
    int blk = logical & 1023;
    int g   = bg & (GG - 1);
    int b   = bg >> 2;

    int t  = threadIdx.x;
    int q  = t & 3;                   // channel quad
    int pi = t >> 2;                  // pixel within block [0,64)
    int pixel = blk * 64 + pi;
    int y = pixel >> 8;
    int x = pixel & (WW - 1);

    const float* pkb = pk + (size_t)bg * HWSZ * GC;   // wave-uniform SGPR base
    const float* offp = off + (size_t)(b*GG*PP*2 + g*PP*2) * HWSZ + pixel;
    const float* wgtp = wgt + (size_t)(b*GG*PP   + g*PP  ) * HWSZ + pixel;
    const float* khp  = kh  + (size_t)(b*GG*KK   + g*KK  ) * HWSZ + pixel;
    const float* kvp  = kv  + (size_t)(b*KK) * HWSZ + pixel;

    // ---- hoisted parameter loads (compiler-managed) ----
    float oxr[PP], oyr[PP], wpall[PP];
#pragma unroll
    for (int p = 0; p < PP; ++p) {
        oxr[p]   = offp[(2*p  )*HWSZ];
        oyr[p]   = offp[(2*p+1)*HWSZ];
        wpall[p] = wgtp[p*HWSZ];
    }
    {
        float khr[KK], kvr[KK];
#pragma unroll
        for (int i = 0; i < KK; ++i) { khr[i] = khp[i*HWSZ]; kvr[i] = kvp[i*HWSZ]; }
#pragma unroll
        for (int p = 0; p < PP; ++p) wpall[p] *= khr[p/KK] * kvr[p%KK];
    }

    // Drain ALL compiler loads before the asm region so the compiler's vmcnt
    // bookkeeping (which cannot see our asm loads) stays correct & harmless.
    asm volatile("s_waitcnt vmcnt(0)" ::: "memory");
    __builtin_amdgcn_sched_barrier(0);

    float acc0 = 0.f, acc1 = 0.f, acc2 = 0.f, acc3 = 0.f;
    const unsigned qoffb = (unsigned)q * 16u;   // byte offset of lane's quadrant
    const float xf = (float)(x - 1);
    const float yf = (float)(y - 1);

    float  w4[3][4];      // folded corner weights, 3-tap rotation
    f32x4  vv[3][4];      // in-flight corner vectors, 3-tap rotation

#define GLOAD(dst, boff) \
    asm volatile("global_load_dwordx4 %0, %1, %2" \
                 : "=v"(dst) : "v"(boff), "s"(pkb) : "memory")

#define WAITV(N) do { \
    asm volatile("s_waitcnt vmcnt(" #N ")" ::: "memory"); \
    __builtin_amdgcn_sched_barrier(0); } while (0)

#define TAP_MATH_LOAD(p) do {                                                   \
    const int kx_ = (p) / KK, ky_ = (p) % KK, bi_ = (p) % 3;                    \
    float wp_ = wpall[p];                                                       \
    float ux_ = xf + (float)kx_ + oxr[p];                                       \
    float uy_ = yf + (float)ky_ + oyr[p];                                       \
    float fx_ = floorf(ux_), fy_ = floorf(uy_);                                 \
    float wx_ = ux_ - fx_,   wy_ = uy_ - fy_;                                   \
    int x0_ = (int)fx_, y0_ = (int)fy_;                                         \
    int x1_ = x0_ + 1,  y1_ = y0_ + 1;                                          \
    bool vx0_ = (unsigned)x0_ < (unsigned)WW;                                   \
    bool vx1_ = (unsigned)x1_ < (unsigned)WW;                                   \
    bool vy0_ = (unsigned)y0_ < (unsigned)HH;                                   \
    bool vy1_ = (unsigned)y1_ < (unsigned)HH;                                   \
    float w00_ = (1.f-wx_)*(1.f-wy_)*wp_; if (!(vx0_ && vy0_)) w00_ = 0.f;      \
    float w01_ =      wx_ *(1.f-wy_)*wp_; if (!(vx1_ && vy0_)) w01_ = 0.f;      \
    float w10_ = (1.f-wx_)*     wy_ *wp_; if (!(vx0_ && vy1_)) w10_ = 0.f;      \
    float w11_ =      wx_ *     wy_ *wp_; if (!(vx1_ && vy1_)) w11_ = 0.f;      \
    int x0c_ = min(max(x0_, 0), WW-1), x1c_ = min(max(x1_, 0), WW-1);           \
    int y0c_ = min(max(y0_, 0), HH-1), y1c_ = min(max(y1_, 0), HH-1);           \
    w4[bi_][0] = w00_; w4[bi_][1] = w01_; w4[bi_][2] = w10_; w4[bi_][3] = w11_; \
    unsigned o00_ = (unsigned)((y0c_*WW + x0c_)*(GC*4)) + qoffb;                \
    unsigned o01_ = (unsigned)((y0c_*WW + x1c_)*(GC*4)) + qoffb;                \
    unsigned o10_ = (unsigned)((y1c_*WW + x0c_)*(GC*4)) + qoffb;                \
    unsigned o11_ = (unsigned)((y1c_*WW + x1c_)*(GC*4)) + qoffb;                \
    GLOAD(vv[bi_][0], o00_);                                                    \
    GLOAD(vv[bi_][1], o01_);                                                    \
    GLOAD(vv[bi_][2], o10_);                                                    \
    GLOAD(vv[bi_][3], o11_);                                                    \
} while (0)

#define TAP_FMA(p) do {                                                         \
    const int bi_ = (p) % 3;                                                    \
    acc0 = fmaf(w4[bi_][0], vv[bi_][0][0], acc0);                               \
    acc1 = fmaf(w4[bi_][0], vv[bi_][0][1], acc1);                               \
    acc2 = fmaf(w4[bi_][0], vv[bi_][0][2], acc2);                               \
    acc3 = fmaf(w4[bi_][0], vv[bi_][0][3], acc3);                               \
    acc0 = fmaf(w4[bi_][1], vv[bi_][1][0], acc0);                               \
    acc1 = fmaf(w4[bi_][1], vv[bi_][1][1], acc1);                               \
    acc2 = fmaf(w4[bi_][1], vv[bi_][1][2], acc2);                               \
    acc3 = fmaf(w4[bi_][1], vv[bi_][1][3], acc3);                               \
    acc0 = fmaf(w4[bi_][2], vv[bi_][2][0], acc0);                               \
    acc1 = fmaf(w4[bi_][2], vv[bi_][2][1], acc1);                               \
    acc2 = fmaf(w4[bi_][2], vv[bi_][2][2], acc2);                               \
    acc3 = fmaf(w4[bi_][2], vv[bi_][2][3], acc3);                               \
    acc0 = fmaf(w4[bi_][3], vv[bi_][3][0], acc0);                               \
    acc1 = fmaf(w4[bi_][3], vv[bi_][3][1], acc1);                               \
    acc2 = fmaf(w4[bi_][3], vv[bi_][3][2], acc2);                               \
    acc3 = fmaf(w4[bi_][3], vv[bi_][3][3], acc3);                               \
} while (0)

    TAP_MATH_LOAD(0);
    TAP_MATH_LOAD(1);
    TAP_MATH_LOAD(2);   WAITV(8); TAP_FMA(0);
    TAP_MATH_LOAD(3);   WAITV(8); TAP_FMA(1);
    TAP_MATH_LOAD(4);   WAITV(8); TAP_FMA(2);
    TAP_MATH_LOAD(5);   WAITV(8); TAP_FMA(3);
    TAP_MATH_LOAD(6);   WAITV(8); TAP_FMA(4);
    TAP_MATH_LOAD(7);   WAITV(8); TAP_FMA(5);
    TAP_MATH_LOAD(8);   WAITV(8); TAP_FMA(6);
    WAITV(4); TAP_FMA(7);
    WAITV(0); TAP_FMA(8);

#undef GLOAD
#undef WAITV
#undef TAP_MATH_LOAD
#undef TAP_FMA

    float* outp = out + (size_t)(b*CC + g*GC + q*4) * HWSZ + pixel;
    outp[0*HWSZ] = acc0;
    outp[1*HWSZ] = acc1;
    outp[2*HWSZ] = acc2;
    outp[3*HWSZ] = acc3;
}

// ---------- Fallback: direct planar kernel (if ws too small) ----------
__global__ __launch_bounds__(256) void misc_filter_direct(
    const float* __restrict__ img,
    const float* __restrict__ kv,
    const float* __restrict__ kh,
    const float* __restrict__ off,
    const float* __restrict__ wgt,
    float* __restrict__ out)
{
    int phys = blockIdx.x;
    int logical = (phys & 7) * (NBLK_RP / 8) + (phys >> 3);
    int y  = logical & (HH - 1);
    int bg = logical >> 8;
    int g  = bg & (GG - 1);
    int b  = bg >> 2;
    int x  = threadIdx.x;

    const float* imgp = img + (size_t)(b*CC + g*GC) * HWSZ;
    int pix = y*WW + x;
    const float* offp = off + (size_t)(b*GG*PP*2 + g*PP*2) * HWSZ + pix;
    const float* wgtp = wgt + (size_t)(b*GG*PP   + g*PP  ) * HWSZ + pix;
    const float* khp  = kh  + (size_t)(b*GG*KK   + g*KK  ) * HWSZ + pix;
    const float* kvp  = kv  + (size_t)(b*KK) * HWSZ + pix;

    float khr[KK], kvr[KK];
#pragma unroll
    for (int i = 0; i < KK; ++i) { khr[i] = khp[i*HWSZ]; kvr[i] = kvp[i*HWSZ]; }
    float acc[GC];
#pragma unroll
    for (int c = 0; c < GC; ++c) acc[c] = 0.f;

#pragma unroll
    for (int p = 0; p < PP; ++p) {
        const int kx = p / KK, ky = p % KK;
        float ox = offp[(2*p  )*HWSZ];
        float oy = offp[(2*p+1)*HWSZ];
        float wp = wgtp[p*HWSZ] * khr[kx] * kvr[ky];
        float ux = (float)(x + kx - 1) + ox;
        float uy = (float)(y + ky - 1) + oy;
        float fx = floorf(ux), fy = floorf(uy);
        float wx = ux - fx,    wy = uy - fy;
        int x0 = (int)fx, y0 = (int)fy;
        int x1 = x0 + 1,  y1 = y0 + 1;
        bool vx0 = (unsigned)x0 < (unsigned)WW;
        bool vx1 = (unsigned)x1 < (unsigned)WW;
        bool vy0 = (unsigned)y0 < (unsigned)HH;
        bool vy1 = (unsigned)y1 < (unsigned)HH;
        float w00 = (1.f-wx)*(1.f-wy)*wp; if (!(vx0 && vy0)) w00 = 0.f;
        float w01 =      wx *(1.f-wy)*wp; if (!(vx1 && vy0)) w01 = 0.f;
        float w10 = (1.f-wx)*     wy *wp; if (!(vx0 && vy1)) w10 = 0.f;
        float w11 =      wx *     wy *wp; if (!(vx1 && vy1)) w11 = 0.f;
        int x0c = min(max(x0, 0), WW-1), x1c = min(max(x1, 0), WW-1);
        int y0c = min(max(y0, 0), HH-1), y1c = min(max(y1, 0), HH-1);
        int i00 = y0c*WW + x0c, i01 = y0c*WW + x1c;
        int i10 = y1c*WW + x0c, i11 = y1c*WW + x1c;
#pragma unroll
        for (int c = 0; c < GC; ++c) {
            const float* pl = imgp + c*HWSZ;
            acc[c] = fmaf(w00, pl[i00], acc[c]);
            acc[c] = fmaf(w01, pl[i01], acc[c]);
            acc[c] = fmaf(w10, pl[i10], acc[c]);
            acc[c] = fmaf(w11, pl[i11], acc[c]);
        }
    }
    float* outp = out + (size_t)(b*CC + g*GC) * HWSZ + pix;
#pragma unroll
    for (int c = 0; c < GC; ++c) outp[c*HWSZ] = acc[c];
}

extern "C" void kernel_launch(void* const* d_in, const int* in_sizes, int n_in,
                              void* d_out, int out_size, void* d_ws, size_t ws_size,
                              hipStream_t stream) {
    const float* img = (const float*)d_in[0];
    const float* kv  = (const float*)d_in[1];
    const float* kh  = (const float*)d_in[2];
    const float* off = (const float*)d_in[3];
    const float* wgt = (const float*)d_in[4];
    float* out = (float*)d_out;

    const size_t need = (size_t)NBG * HWSZ * GC * sizeof(float);  // 33.5 MB
    if (ws_size >= need) {
        float* pk = (float*)d_ws;
        repack_kernel<<<dim3(NBLK_RP), dim3(WW), 0, stream>>>(img, pk);
        misc_filter_coop<<<dim3(NBLK_MAIN), dim3(256), 0, stream>>>(pk, kv, kh, off, wgt, out);
    } else {
        misc_filter_direct<<<dim3(NBLK_RP), dim3(WW), 0, stream>>>(img, kv, kh, off, wgt, out);
    }
}